// Round 2
// baseline (768.907 us; speedup 1.0000x reference)
//
#include <hip/hip_runtime.h>

// HeteroGNN on MI355X. Inputs/weights/output fp32 (per reference); intermediates bf16.
//   CSR build (count -> scan -> fill)
//   agg0  : seg-mean x_host->flow, x_flow->host (64d), CSR gather, fp32 acc -> bf16
//   G1    : h_flow = lrelu([agg0f|x_flow] @ [W0_hf_l;W0_hf_r] + b0_hf)   M=200000  (bf16 out)
//   G2    : h_host = lrelu([agg0h|x_host] @ [W0_fh_l;W0_fh_r] + b0_fh)   M=20000
//   G3    : hT     = h_host @ W1_hf_l   (transform BEFORE mean: linearity)
//   agg1  : seg-mean hT -> flow (128d)
//   G4    : out = (lrelu(agg1 + b1_hf + h_flow @ W1_hf_r)) @ W_out + b_out   (fp32 out, fused)
// g_host dead in reference -> W1_fh_* unused.

#define N_HOST 20000
#define N_FLOW 200000
#define NEDGE  600000
#define D_IN   64
#define D_H    128
#define D_OUT  32
#define NSEG   (N_FLOW + N_HOST)
#define NB     108                 // ceil(NSEG / 2048)

typedef unsigned short u16;
typedef unsigned int   u32;

__device__ __forceinline__ float bfh(u16 h) { return __uint_as_float(((u32)h) << 16); }
__device__ __forceinline__ u16 fbh(float f) {
    u32 u = __float_as_uint(f);
    return (u16)((u + 0x7fffu + ((u >> 16) & 1u)) >> 16);   // RNE
}
__device__ __forceinline__ u32 packbf(float x, float y) {
    return (u32)fbh(x) | ((u32)fbh(y) << 16);
}

// ---------------- CSR build ----------------
__global__ void k_count(const int* __restrict__ dst_hf, const int* __restrict__ dst_fh,
                        int* __restrict__ deg) {
    int t = blockIdx.x * 256 + threadIdx.x;
    if (t < NEDGE)               atomicAdd(&deg[dst_hf[t]], 1);
    else if (t < 2 * NEDGE)      atomicAdd(&deg[N_FLOW + dst_fh[t - NEDGE]], 1);
}

__global__ void k_scan1(const int* __restrict__ deg, int* __restrict__ part) {
    int b = blockIdx.x, t = threadIdx.x;
    int s = 0;
#pragma unroll
    for (int i = 0; i < 8; i++) {
        int idx = b * 2048 + t + i * 256;
        if (idx < NSEG) s += deg[idx];
    }
    for (int o = 32; o > 0; o >>= 1) s += __shfl_down(s, o, 64);
    __shared__ int red[4];
    int lane = t & 63, wid = t >> 6;
    if (lane == 0) red[wid] = s;
    __syncthreads();
    if (t == 0) part[b] = red[0] + red[1] + red[2] + red[3];
}

__global__ void k_scan2(int* __restrict__ part) {
    __shared__ int sp[256];
    int t = threadIdx.x;
    int v = (t < NB) ? part[t] : 0;
    sp[t] = v;
    __syncthreads();
    for (int d = 1; d < 256; d <<= 1) {
        int x = (t >= d) ? sp[t - d] : 0;
        __syncthreads();
        sp[t] += x;
        __syncthreads();
    }
    if (t < NB) part[t] = sp[t] - v;   // exclusive
}

__global__ void k_scan3(const int* __restrict__ deg, const int* __restrict__ part,
                        int* __restrict__ off) {
    __shared__ int sv[2048];
    __shared__ int ts[256];
    int b = blockIdx.x, t = threadIdx.x;
    int base = b * 2048;
#pragma unroll
    for (int i = 0; i < 8; i++) {
        int idx = base + t + i * 256;
        sv[t + i * 256] = (idx < NSEG) ? deg[idx] : 0;
    }
    __syncthreads();
    int loc[8]; int s = 0;
#pragma unroll
    for (int j = 0; j < 8; j++) { loc[j] = s; s += sv[t * 8 + j]; }
    ts[t] = s;
    __syncthreads();
    for (int d = 1; d < 256; d <<= 1) {
        int x = (t >= d) ? ts[t - d] : 0;
        __syncthreads();
        ts[t] += x;
        __syncthreads();
    }
    int b2 = part[b] + ts[t] - s;
#pragma unroll
    for (int j = 0; j < 8; j++) {
        int idx = base + t * 8 + j;
        if (idx < NSEG) off[idx] = b2 + loc[j];
    }
}

__global__ void k_fill(const int* __restrict__ src_hf, const int* __restrict__ dst_hf,
                       const int* __restrict__ src_fh, const int* __restrict__ dst_fh,
                       int* __restrict__ off, int* __restrict__ csr) {
    int t = blockIdx.x * 256 + threadIdx.x;
    if (t < NEDGE) {
        int d = dst_hf[t];
        int p = atomicAdd(&off[d], 1);
        csr[p] = src_hf[t];
    } else if (t < 2 * NEDGE) {
        int e = t - NEDGE;
        int d = dst_fh[e];
        int p = atomicAdd(&off[N_FLOW + d], 1);
        csr[p] = src_fh[e];
    }
    // post-fill: off[i] == segment END; start(i) = off[i-1] (0 for i==0)
}

// ---------------- aggregation ----------------
__global__ void k_agg0(const float* __restrict__ x_host, const float* __restrict__ x_flow,
                       const int* __restrict__ off, const int* __restrict__ csr,
                       u16* __restrict__ agg0f, u16* __restrict__ agg0h) {
    int w = blockIdx.x * 4 + (threadIdx.x >> 6);   // one wave per node
    int lane = threadIdx.x & 63;
    if (w >= NSEG) return;
    int start = (w == 0) ? 0 : off[w - 1];
    int end = off[w];
    float acc = 0.f;
    if (w < N_FLOW) {
        for (int e = start; e < end; e++) {
            int s = csr[e];
            acc += x_host[s * D_IN + lane];
        }
        float inv = (end > start) ? 1.f / (float)(end - start) : 0.f;
        agg0f[w * D_IN + lane] = fbh(acc * inv);
    } else {
        int j = w - N_FLOW;
        for (int e = start; e < end; e++) {
            int s = csr[e];
            acc += x_flow[s * D_IN + lane];
        }
        float inv = (end > start) ? 1.f / (float)(end - start) : 0.f;
        agg0h[j * D_IN + lane] = fbh(acc * inv);
    }
}

__global__ void k_agg1(const u16* __restrict__ hT, const int* __restrict__ off,
                       const int* __restrict__ csr, u16* __restrict__ agg1m) {
    int w = blockIdx.x * 4 + (threadIdx.x >> 6);
    int lane = threadIdx.x & 63;
    if (w >= N_FLOW) return;
    int start = (w == 0) ? 0 : off[w - 1];
    int end = off[w];
    float ax = 0.f, ay = 0.f;
    for (int e = start; e < end; e++) {
        int s = csr[e];
        u32 u = *(const u32*)(hT + s * D_H + lane * 2);
        ax += __uint_as_float(u << 16);
        ay += __uint_as_float(u & 0xffff0000u);
    }
    float inv = (end > start) ? 1.f / (float)(end - start) : 0.f;
    *(u32*)(agg1m + w * D_H + lane * 2) = packbf(ax * inv, ay * inv);
}

// ---------------- GEMM: 64-row x 64-col tile, K=128 ----------------
// DUAL: A = [A1 bf16 (64) | A2 fp32 (64)], W = [W1;W2] fp32 stacked. OUT bf16 stride 128.
// non-DUAL: A1 bf16 stride 128, W1 fp32 [128][128].
template <bool DUAL, bool RELU>
__global__ __launch_bounds__(256) void k_gemm64(
    const u16* __restrict__ A1, const float* __restrict__ A2,
    const float* __restrict__ W1, const float* __restrict__ W2,
    const float* __restrict__ bias, u16* __restrict__ OUT, int M) {
    __shared__ __align__(16) u16 sA[128 * 68];   // transposed [k][row], stride 68
    __shared__ __align__(16) float sW[128 * 64]; // [k][col] fp32
    const int t = threadIdx.x;
    const int m0 = blockIdx.x * 64;
    const int c0 = blockIdx.y * 64;
#pragma unroll
    for (int i = 0; i < 8; i++) {
        int q = t + i * 256;
        int k = q >> 4;
        int c = (q & 15) << 2;
        const float* Wp = W1;
        int kk = k;
        if (DUAL) { if (k >= 64) { Wp = W2; kk = k - 64; } }
        *(float4*)(&sW[k * 64 + c]) = *(const float4*)(Wp + kk * D_H + c0 + c);
    }
#pragma unroll
    for (int i = 0; i < 8; i++) {
        int q = t + i * 256;
        int r = q >> 5;
        int kc = (q & 31) << 2;
        int row = m0 + r;
        u16 e0 = 0, e1 = 0, e2 = 0, e3 = 0;
        if (row < M) {
            if (DUAL) {
                if (kc < 64) {
                    uint2 uv = *(const uint2*)(A1 + row * 64 + kc);
                    e0 = (u16)(uv.x & 0xffffu); e1 = (u16)(uv.x >> 16);
                    e2 = (u16)(uv.y & 0xffffu); e3 = (u16)(uv.y >> 16);
                } else {
                    float4 fv = *(const float4*)(A2 + row * 64 + (kc - 64));
                    e0 = fbh(fv.x); e1 = fbh(fv.y); e2 = fbh(fv.z); e3 = fbh(fv.w);
                }
            } else {
                uint2 uv = *(const uint2*)(A1 + row * 128 + kc);
                e0 = (u16)(uv.x & 0xffffu); e1 = (u16)(uv.x >> 16);
                e2 = (u16)(uv.y & 0xffffu); e3 = (u16)(uv.y >> 16);
            }
        }
        sA[(kc + 0) * 68 + r] = e0;
        sA[(kc + 1) * 68 + r] = e1;
        sA[(kc + 2) * 68 + r] = e2;
        sA[(kc + 3) * 68 + r] = e3;
    }
    __syncthreads();
    const int g = t & 15, rg = t >> 4;   // cols g*4..+3, rows rg*4..+3
    float acc[4][4];
#pragma unroll
    for (int i = 0; i < 4; i++)
#pragma unroll
        for (int j = 0; j < 4; j++) acc[i][j] = 0.f;
#pragma unroll 4
    for (int k = 0; k < 128; k++) {
        const float4 wv = *(const float4*)(&sW[k * 64 + (g << 2)]);
        const uint2 av = *(const uint2*)(&sA[k * 68 + (rg << 2)]);
        float a[4];
        a[0] = __uint_as_float(av.x << 16);
        a[1] = __uint_as_float(av.x & 0xffff0000u);
        a[2] = __uint_as_float(av.y << 16);
        a[3] = __uint_as_float(av.y & 0xffff0000u);
#pragma unroll
        for (int i = 0; i < 4; i++) {
            acc[i][0] += a[i] * wv.x;
            acc[i][1] += a[i] * wv.y;
            acc[i][2] += a[i] * wv.z;
            acc[i][3] += a[i] * wv.w;
        }
    }
    float bv[4];
#pragma unroll
    for (int j = 0; j < 4; j++) bv[j] = bias ? bias[c0 + (g << 2) + j] : 0.f;
#pragma unroll
    for (int i = 0; i < 4; i++) {
        int row = m0 + (rg << 2) + i;
        if (row < M) {
            float v[4];
#pragma unroll
            for (int j = 0; j < 4; j++) {
                v[j] = acc[i][j] + bv[j];
                if (RELU) v[j] = v[j] > 0.f ? v[j] : 0.01f * v[j];
            }
            uint2 o;
            o.x = packbf(v[0], v[1]);
            o.y = packbf(v[2], v[3]);
            *(uint2*)(OUT + row * D_H + c0 + (g << 2)) = o;
        }
    }
}

// ---------------- fused final: g=lrelu(A@W + agg1 + b1); out=g@Wout+bout (fp32 out) ----------------
__global__ __launch_bounds__(256) void k_gemm_final(
    const u16* __restrict__ A, const float* __restrict__ W,
    const float* __restrict__ b1, const u16* __restrict__ aggm,
    const float* __restrict__ Wout, const float* __restrict__ bout,
    float* __restrict__ OUT, int M) {
    __shared__ __align__(16) char smem[50176];
    u16* sA = (u16*)smem;                 // phase1: [128][68] transposed A (bf16)
    u16* sW = (u16*)(smem + 17408);       // phase1: [128][128] bf16 W
    float* sG = (float*)smem;             // phase2: [64][132] fp32 g tile
    float* sWo = (float*)(smem + 33792);  // phase2: [128][32] fp32 W_out
    const int t = threadIdx.x;
    const int m0 = blockIdx.x * 64;
#pragma unroll
    for (int i = 0; i < 8; i++) {
        int q = t + i * 256;
        int r = q >> 5;
        int kc = (q & 31) << 2;
        int row = m0 + r;
        uint2 uv = make_uint2(0u, 0u);
        if (row < M) uv = *(const uint2*)(A + row * D_H + kc);
        sA[(kc + 0) * 68 + r] = (u16)(uv.x & 0xffffu);
        sA[(kc + 1) * 68 + r] = (u16)(uv.x >> 16);
        sA[(kc + 2) * 68 + r] = (u16)(uv.y & 0xffffu);
        sA[(kc + 3) * 68 + r] = (u16)(uv.y >> 16);
    }
#pragma unroll
    for (int i = 0; i < 16; i++) {
        int q = t + i * 256;               // q < 4096
        float4 fv = *(const float4*)(W + q * 4);
        uint2 o;
        o.x = packbf(fv.x, fv.y);
        o.y = packbf(fv.z, fv.w);
        *(uint2*)(sW + q * 4) = o;
    }
    __syncthreads();
    const int g = t & 15, rg = t >> 4;   // cols {g*4..+3, 64+g*4..+3}, rows rg*4..+3
    float acc[4][8];
#pragma unroll
    for (int i = 0; i < 4; i++)
#pragma unroll
        for (int j = 0; j < 8; j++) acc[i][j] = 0.f;
#pragma unroll 2
    for (int k = 0; k < 128; k++) {
        const uint2 av = *(const uint2*)(sA + k * 68 + (rg << 2));
        const uint2 w0 = *(const uint2*)(sW + k * 128 + (g << 2));
        const uint2 w1 = *(const uint2*)(sW + k * 128 + 64 + (g << 2));
        float a[4], wv[8];
        a[0] = __uint_as_float(av.x << 16);
        a[1] = __uint_as_float(av.x & 0xffff0000u);
        a[2] = __uint_as_float(av.y << 16);
        a[3] = __uint_as_float(av.y & 0xffff0000u);
        wv[0] = __uint_as_float(w0.x << 16);
        wv[1] = __uint_as_float(w0.x & 0xffff0000u);
        wv[2] = __uint_as_float(w0.y << 16);
        wv[3] = __uint_as_float(w0.y & 0xffff0000u);
        wv[4] = __uint_as_float(w1.x << 16);
        wv[5] = __uint_as_float(w1.x & 0xffff0000u);
        wv[6] = __uint_as_float(w1.y << 16);
        wv[7] = __uint_as_float(w1.y & 0xffff0000u);
#pragma unroll
        for (int i = 0; i < 4; i++)
#pragma unroll
            for (int j = 0; j < 8; j++) acc[i][j] += a[i] * wv[j];
    }
    __syncthreads();   // phase-1 LDS reads done; smem reused
    {
        float bb[8];
#pragma unroll
        for (int j = 0; j < 4; j++) {
            bb[j] = b1[(g << 2) + j];
            bb[4 + j] = b1[64 + (g << 2) + j];
        }
#pragma unroll
        for (int i = 0; i < 4; i++) {
            int r = (rg << 2) + i;
            int row = m0 + r;
            uint2 q0 = make_uint2(0u, 0u), q1 = make_uint2(0u, 0u);
            if (row < M) {
                q0 = *(const uint2*)(aggm + row * D_H + (g << 2));
                q1 = *(const uint2*)(aggm + row * D_H + 64 + (g << 2));
            }
            float av_[8];
            av_[0] = __uint_as_float(q0.x << 16);
            av_[1] = __uint_as_float(q0.x & 0xffff0000u);
            av_[2] = __uint_as_float(q0.y << 16);
            av_[3] = __uint_as_float(q0.y & 0xffff0000u);
            av_[4] = __uint_as_float(q1.x << 16);
            av_[5] = __uint_as_float(q1.x & 0xffff0000u);
            av_[6] = __uint_as_float(q1.y << 16);
            av_[7] = __uint_as_float(q1.y & 0xffff0000u);
#pragma unroll
            for (int j = 0; j < 8; j++) {
                float v = acc[i][j] + av_[j] + bb[j];
                v = v > 0.f ? v : 0.01f * v;
                int c = (j < 4) ? ((g << 2) + j) : (64 + (g << 2) + (j - 4));
                sG[r * 132 + c] = v;
            }
        }
    }
#pragma unroll
    for (int i = 0; i < 4; i++) {
        int q = t + i * 256;               // q < 1024
        *(float4*)(sWo + q * 4) = *(const float4*)(Wout + q * 4);
    }
    __syncthreads();
    const int og = t & 7, orr = t >> 3;
    const int r0 = orr * 2;
    float o0[4] = {0.f, 0.f, 0.f, 0.f}, o1[4] = {0.f, 0.f, 0.f, 0.f};
#pragma unroll 2
    for (int k = 0; k < 128; k++) {
        float g0 = sG[r0 * 132 + k];
        float g1 = sG[(r0 + 1) * 132 + k];
        float4 wv = *(const float4*)(sWo + k * 32 + (og << 2));
        o0[0] += g0 * wv.x; o0[1] += g0 * wv.y; o0[2] += g0 * wv.z; o0[3] += g0 * wv.w;
        o1[0] += g1 * wv.x; o1[1] += g1 * wv.y; o1[2] += g1 * wv.z; o1[3] += g1 * wv.w;
    }
    float bo[4];
#pragma unroll
    for (int j = 0; j < 4; j++) bo[j] = bout[(og << 2) + j];
    int row0 = m0 + r0;
    if (row0 < M) {
        *(float4*)(OUT + row0 * D_OUT + (og << 2)) =
            make_float4(o0[0] + bo[0], o0[1] + bo[1], o0[2] + bo[2], o0[3] + bo[3]);
    }
    if (row0 + 1 < M) {
        *(float4*)(OUT + (row0 + 1) * D_OUT + (og << 2)) =
            make_float4(o1[0] + bo[0], o1[1] + bo[1], o1[2] + bo[2], o1[3] + bo[3]);
    }
}

extern "C" void kernel_launch(void* const* d_in, const int* in_sizes, int n_in,
                              void* d_out, int out_size, void* d_ws, size_t ws_size,
                              hipStream_t stream) {
    const float* x_host  = (const float*)d_in[0];
    const float* x_flow  = (const float*)d_in[1];
    const int* src_hf  = (const int*)d_in[2];
    const int* dst_hf  = (const int*)d_in[3];
    const int* src_fh  = (const int*)d_in[4];
    const int* dst_fh  = (const int*)d_in[5];
    const float* W0_hf_l = (const float*)d_in[6];
    const float* W0_hf_r = (const float*)d_in[7];
    const float* b0_hf   = (const float*)d_in[8];
    const float* W0_fh_l = (const float*)d_in[9];
    const float* W0_fh_r = (const float*)d_in[10];
    const float* b0_fh   = (const float*)d_in[11];
    const float* W1_hf_l = (const float*)d_in[12];
    const float* W1_hf_r = (const float*)d_in[13];
    const float* b1_hf   = (const float*)d_in[14];
    const float* W_out   = (const float*)d_in[18];
    const float* b_out   = (const float*)d_in[19];
    float* out = (float*)d_out;

    // workspace layout (bytes), lifetime-aliased; total ~114.1 MB
    char* ws = (char*)d_ws;
    int* off    = (int*)(ws + 0);            //   880,000
    int* csr    = (int*)(ws + 880000);       // 4,800,000
    u16* h_flow = (u16*)(ws + 5680000);      // 51,200,000 (bf16, live to end)
    u16* hT     = (u16*)(ws + 56880000);     //  5,120,000 (bf16)
    u16* agg1m  = (u16*)(ws + 62000000);     // 51,200,000 (bf16) -- region reused:
    u16* agg0f  = (u16*)(ws + 62000000);     //   25,600,000 (dead after G1)
    u16* agg0h  = (u16*)(ws + 87600000);     //    2,560,000 (dead after G2)
    u16* h_host = (u16*)(ws + 90160000);     //    5,120,000 (dead after G3)
    int* deg    = (int*)(ws + 113200000);    //   880,000
    int* part   = (int*)(ws + 114080000);    //       448

    hipMemsetAsync(deg, 0, NSEG * sizeof(int), stream);
    k_count<<<(2 * NEDGE + 255) / 256, 256, 0, stream>>>(dst_hf, dst_fh, deg);
    k_scan1<<<NB, 256, 0, stream>>>(deg, part);
    k_scan2<<<1, 256, 0, stream>>>(part);
    k_scan3<<<NB, 256, 0, stream>>>(deg, part, off);
    k_fill<<<(2 * NEDGE + 255) / 256, 256, 0, stream>>>(src_hf, dst_hf, src_fh, dst_fh, off, csr);
    k_agg0<<<NSEG / 4, 256, 0, stream>>>(x_host, x_flow, off, csr, agg0f, agg0h);
    k_gemm64<true, true><<<dim3(3125, 2), 256, 0, stream>>>(
        agg0f, x_flow, W0_hf_l, W0_hf_r, b0_hf, h_flow, N_FLOW);
    k_gemm64<true, true><<<dim3(313, 2), 256, 0, stream>>>(
        agg0h, x_host, W0_fh_l, W0_fh_r, b0_fh, h_host, N_HOST);
    k_gemm64<false, false><<<dim3(313, 2), 256, 0, stream>>>(
        h_host, nullptr, W1_hf_l, nullptr, nullptr, hT, N_HOST);
    k_agg1<<<N_FLOW / 4, 256, 0, stream>>>(hT, off, csr, agg1m);
    k_gemm_final<<<3125, 256, 0, stream>>>(h_flow, W1_hf_r, b1_hf, agg1m, W_out, b_out, out, N_FLOW);
}

// Round 3
// 615.838 us; speedup vs baseline: 1.2486x; 1.2486x over previous
//
#include <hip/hip_runtime.h>

// HeteroGNN on MI355X. Inputs/weights/output fp32 (per reference); intermediates bf16.
// Round 3: all GEMMs on v_mfma_f32_16x16x32_bf16. Weights pre-transposed to bf16 WT[n][k].
//   CSR build (count -> scan -> fill)
//   agg0  : seg-mean x_host->flow, x_flow->host (64d)
//   G1    : h_flow = lrelu([agg0f|x_flow] @ WT0_hf^T + b0_hf)   M=200000  (MFMA)
//   G2    : h_host = lrelu([agg0h|x_host] @ WT0_fh^T + b0_fh)   M=20000   (MFMA)
//   G3    : hT     = h_host @ W1_hf_l  (transform BEFORE mean)            (MFMA)
//   agg1  : seg-mean hT -> flow (128d)
//   G4    : out = lrelu(h_flow@W1_hf_r + agg1 + b1) @ W_out + b_out  (fused 2-phase MFMA)
// g_host dead in reference -> W1_fh_* unused.

#define N_HOST 20000
#define N_FLOW 200000
#define NEDGE  600000
#define D_IN   64
#define D_H    128
#define D_OUT  32
#define NSEG   (N_FLOW + N_HOST)
#define NB     108                 // ceil(NSEG / 2048)

typedef unsigned short u16;
typedef unsigned int   u32;
typedef short bf16x8 __attribute__((ext_vector_type(8)));
typedef float f32x4  __attribute__((ext_vector_type(4)));

__device__ __forceinline__ float bfh(u16 h) { return __uint_as_float(((u32)h) << 16); }
__device__ __forceinline__ u16 fbh(float f) {
    u32 u = __float_as_uint(f);
    return (u16)((u + 0x7fffu + ((u >> 16) & 1u)) >> 16);   // RNE
}
__device__ __forceinline__ u32 packbf(float x, float y) {
    return (u32)fbh(x) | ((u32)fbh(y) << 16);
}

// ---------------- weight pre-transpose: WT[n][k] bf16 ----------------
__global__ void k_prep(const float* __restrict__ W0_hf_l, const float* __restrict__ W0_hf_r,
                       const float* __restrict__ W0_fh_l, const float* __restrict__ W0_fh_r,
                       const float* __restrict__ W1_l, const float* __restrict__ W1_r,
                       const float* __restrict__ Wout,
                       u16* __restrict__ WT0_hf, u16* __restrict__ WT0_fh,
                       u16* __restrict__ WT1_l, u16* __restrict__ WT1_r,
                       u16* __restrict__ WTo) {
    int b = blockIdx.x, t = threadIdx.x;
    u16 tmp[8];
    if (b < 32) {
        int e = (b & 7) * 2048 + t * 8;
        int n = e >> 7, k0 = e & 127;
        if (b < 8) {
#pragma unroll
            for (int j = 0; j < 8; j++) {
                int k = k0 + j;
                tmp[j] = fbh(k < 64 ? W0_hf_l[k * D_H + n] : W0_hf_r[(k - 64) * D_H + n]);
            }
            *(uint4*)(WT0_hf + n * 128 + k0) = *(uint4*)tmp;
        } else if (b < 16) {
#pragma unroll
            for (int j = 0; j < 8; j++) {
                int k = k0 + j;
                tmp[j] = fbh(k < 64 ? W0_fh_l[k * D_H + n] : W0_fh_r[(k - 64) * D_H + n]);
            }
            *(uint4*)(WT0_fh + n * 128 + k0) = *(uint4*)tmp;
        } else if (b < 24) {
#pragma unroll
            for (int j = 0; j < 8; j++) tmp[j] = fbh(W1_l[(k0 + j) * D_H + n]);
            *(uint4*)(WT1_l + n * 128 + k0) = *(uint4*)tmp;
        } else {
#pragma unroll
            for (int j = 0; j < 8; j++) tmp[j] = fbh(W1_r[(k0 + j) * D_H + n]);
            *(uint4*)(WT1_r + n * 128 + k0) = *(uint4*)tmp;
        }
    } else {
        int e = (b - 32) * 2048 + t * 8;
        int n = e >> 7, k0 = e & 127;
#pragma unroll
        for (int j = 0; j < 8; j++) tmp[j] = fbh(Wout[(k0 + j) * D_OUT + n]);
        *(uint4*)(WTo + n * 128 + k0) = *(uint4*)tmp;
    }
}

// ---------------- CSR build ----------------
__global__ void k_count(const int* __restrict__ dst_hf, const int* __restrict__ dst_fh,
                        int* __restrict__ deg) {
    int t = blockIdx.x * 256 + threadIdx.x;
    if (t < NEDGE)               atomicAdd(&deg[dst_hf[t]], 1);
    else if (t < 2 * NEDGE)      atomicAdd(&deg[N_FLOW + dst_fh[t - NEDGE]], 1);
}

__global__ void k_scan1(const int* __restrict__ deg, int* __restrict__ part) {
    int b = blockIdx.x, t = threadIdx.x;
    int s = 0;
#pragma unroll
    for (int i = 0; i < 8; i++) {
        int idx = b * 2048 + t + i * 256;
        if (idx < NSEG) s += deg[idx];
    }
    for (int o = 32; o > 0; o >>= 1) s += __shfl_down(s, o, 64);
    __shared__ int red[4];
    int lane = t & 63, wid = t >> 6;
    if (lane == 0) red[wid] = s;
    __syncthreads();
    if (t == 0) part[b] = red[0] + red[1] + red[2] + red[3];
}

__global__ void k_scan2(int* __restrict__ part) {
    __shared__ int sp[256];
    int t = threadIdx.x;
    int v = (t < NB) ? part[t] : 0;
    sp[t] = v;
    __syncthreads();
    for (int d = 1; d < 256; d <<= 1) {
        int x = (t >= d) ? sp[t - d] : 0;
        __syncthreads();
        sp[t] += x;
        __syncthreads();
    }
    if (t < NB) part[t] = sp[t] - v;   // exclusive
}

__global__ void k_scan3(const int* __restrict__ deg, const int* __restrict__ part,
                        int* __restrict__ off) {
    __shared__ int sv[2048];
    __shared__ int ts[256];
    int b = blockIdx.x, t = threadIdx.x;
    int base = b * 2048;
#pragma unroll
    for (int i = 0; i < 8; i++) {
        int idx = base + t + i * 256;
        sv[t + i * 256] = (idx < NSEG) ? deg[idx] : 0;
    }
    __syncthreads();
    int loc[8]; int s = 0;
#pragma unroll
    for (int j = 0; j < 8; j++) { loc[j] = s; s += sv[t * 8 + j]; }
    ts[t] = s;
    __syncthreads();
    for (int d = 1; d < 256; d <<= 1) {
        int x = (t >= d) ? ts[t - d] : 0;
        __syncthreads();
        ts[t] += x;
        __syncthreads();
    }
    int b2 = part[b] + ts[t] - s;
#pragma unroll
    for (int j = 0; j < 8; j++) {
        int idx = base + t * 8 + j;
        if (idx < NSEG) off[idx] = b2 + loc[j];
    }
}

__global__ void k_fill(const int* __restrict__ src_hf, const int* __restrict__ dst_hf,
                       const int* __restrict__ src_fh, const int* __restrict__ dst_fh,
                       int* __restrict__ off, int* __restrict__ csr) {
    int t = blockIdx.x * 256 + threadIdx.x;
    if (t < NEDGE) {
        int d = dst_hf[t];
        int p = atomicAdd(&off[d], 1);
        csr[p] = src_hf[t];
    } else if (t < 2 * NEDGE) {
        int e = t - NEDGE;
        int d = dst_fh[e];
        int p = atomicAdd(&off[N_FLOW + d], 1);
        csr[p] = src_fh[e];
    }
    // post-fill: off[i] == segment END; start(i) = off[i-1] (0 for i==0)
}

// ---------------- aggregation ----------------
__global__ void k_agg0(const float* __restrict__ x_host, const float* __restrict__ x_flow,
                       const int* __restrict__ off, const int* __restrict__ csr,
                       u16* __restrict__ agg0f, u16* __restrict__ agg0h) {
    int w = blockIdx.x * 4 + (threadIdx.x >> 6);   // one wave per node
    int lane = threadIdx.x & 63;
    if (w >= NSEG) return;
    int start = (w == 0) ? 0 : off[w - 1];
    int end = off[w];
    float acc = 0.f;
    if (w < N_FLOW) {
        for (int e = start; e < end; e++) {
            int s = csr[e];
            acc += x_host[s * D_IN + lane];
        }
        float inv = (end > start) ? 1.f / (float)(end - start) : 0.f;
        agg0f[w * D_IN + lane] = fbh(acc * inv);
    } else {
        int j = w - N_FLOW;
        for (int e = start; e < end; e++) {
            int s = csr[e];
            acc += x_flow[s * D_IN + lane];
        }
        float inv = (end > start) ? 1.f / (float)(end - start) : 0.f;
        agg0h[j * D_IN + lane] = fbh(acc * inv);
    }
}

__global__ void k_agg1(const u16* __restrict__ hT, const int* __restrict__ off,
                       const int* __restrict__ csr, u16* __restrict__ agg1m) {
    int w = blockIdx.x * 4 + (threadIdx.x >> 6);
    int lane = threadIdx.x & 63;
    if (w >= N_FLOW) return;
    int start = (w == 0) ? 0 : off[w - 1];
    int end = off[w];
    float ax = 0.f, ay = 0.f;
    for (int e = start; e < end; e++) {
        int s = csr[e];
        u32 u = *(const u32*)(hT + s * D_H + lane * 2);
        ax += __uint_as_float(u << 16);
        ay += __uint_as_float(u & 0xffff0000u);
    }
    float inv = (end > start) ? 1.f / (float)(end - start) : 0.f;
    *(u32*)(agg1m + w * D_H + lane * 2) = packbf(ax * inv, ay * inv);
}

// ---------------- MFMA GEMM: 64-row tile x N=128, K=128, one-shot ----------------
// A-frag: A[m=lane&15][k=quad*8+j]; B-frag: WT[n=lane&15][k=quad*8+j]; C: col=lane&15,row=quad*4+reg.
// DUAL: A = [A1 bf16 64d | A2 fp32 64d]. else A1 bf16 stride 128. OUT bf16 [M][128].
template <bool DUAL, bool RELU>
__global__ __launch_bounds__(256) void k_mfma(
    const u16* __restrict__ A1, const float* __restrict__ A2,
    const u16* __restrict__ WT, const float* __restrict__ bias,
    u16* __restrict__ OUT, int M) {
    __shared__ __align__(16) u16 sA[64 * 136];    // [r][k] pad->stride 136 (16B aligned rows)
    __shared__ __align__(16) u16 sW[128 * 136];   // [n][k]
    const int t = threadIdx.x;
    const int m0 = blockIdx.x * 64;
#pragma unroll
    for (int i = 0; i < 8; i++) {
        int q = t + i * 256;
        int row = q >> 4, seg = q & 15;
        *(uint4*)(&sW[row * 136 + seg * 8]) = *(const uint4*)(WT + row * 128 + seg * 8);
    }
#pragma unroll
    for (int i = 0; i < 4; i++) {
        int q = t + i * 256;
        int r = q >> 4, seg = q & 15;
        int row = m0 + r;
        uint4 val = make_uint4(0u, 0u, 0u, 0u);
        if (row < M) {
            if (DUAL) {
                if (seg < 8) {
                    val = *(const uint4*)(A1 + row * 64 + seg * 8);
                } else {
                    float4 f0 = *(const float4*)(A2 + row * 64 + (seg - 8) * 8);
                    float4 f1 = *(const float4*)(A2 + row * 64 + (seg - 8) * 8 + 4);
                    val.x = packbf(f0.x, f0.y); val.y = packbf(f0.z, f0.w);
                    val.z = packbf(f1.x, f1.y); val.w = packbf(f1.z, f1.w);
                }
            } else {
                val = *(const uint4*)(A1 + row * 128 + seg * 8);
            }
        }
        *(uint4*)(&sA[r * 136 + seg * 8]) = val;
    }
    __syncthreads();
    const int w = t >> 6, ln = t & 63, l15 = ln & 15, quad = ln >> 4;
    const u16* pA = sA + (w * 16 + l15) * 136 + quad * 8;
    const u16* pB = sW + l15 * 136 + quad * 8;
    f32x4 acc[8];
#pragma unroll
    for (int tt = 0; tt < 8; tt++) acc[tt] = (f32x4){0.f, 0.f, 0.f, 0.f};
#pragma unroll
    for (int s = 0; s < 4; s++) {
        bf16x8 a = *(const bf16x8*)(pA + s * 32);
#pragma unroll
        for (int tt = 0; tt < 8; tt++) {
            bf16x8 b = *(const bf16x8*)(pB + tt * 2176 + s * 32);
            acc[tt] = __builtin_amdgcn_mfma_f32_16x16x32_bf16(a, b, acc[tt], 0, 0, 0);
        }
    }
#pragma unroll
    for (int tt = 0; tt < 8; tt++) {
        int col = tt * 16 + l15;
        float bv = bias ? bias[col] : 0.f;
#pragma unroll
        for (int i = 0; i < 4; i++) {
            int row = m0 + w * 16 + quad * 4 + i;
            if (row < M) {
                float v = acc[tt][i] + bv;
                if (RELU) v = v > 0.f ? v : 0.01f * v;
                OUT[row * D_H + col] = fbh(v);
            }
        }
    }
}

// ---------------- fused final: g=lrelu(A@W1r + agg1 + b1); out=g@Wout+bout ----------------
__global__ __launch_bounds__(256) void k_final(
    const u16* __restrict__ A, const u16* __restrict__ WT1r,
    const float* __restrict__ b1, const u16* __restrict__ aggm,
    const u16* __restrict__ WTo, const float* __restrict__ bout,
    float* __restrict__ OUT, int M) {
    __shared__ __align__(16) u16 sA[64 * 136];    // phase1 A tile; phase2 g tile (wave-private rows)
    __shared__ __align__(16) u16 sW[128 * 136];
    const int t = threadIdx.x;
    const int m0 = blockIdx.x * 64;
#pragma unroll
    for (int i = 0; i < 8; i++) {
        int q = t + i * 256;
        int row = q >> 4, seg = q & 15;
        *(uint4*)(&sW[row * 136 + seg * 8]) = *(const uint4*)(WT1r + row * 128 + seg * 8);
    }
#pragma unroll
    for (int i = 0; i < 4; i++) {
        int q = t + i * 256;
        int r = q >> 4, seg = q & 15;
        int row = m0 + r;
        uint4 val = make_uint4(0u, 0u, 0u, 0u);
        if (row < M) val = *(const uint4*)(A + row * D_H + seg * 8);
        *(uint4*)(&sA[r * 136 + seg * 8]) = val;
    }
    __syncthreads();
    const int w = t >> 6, ln = t & 63, l15 = ln & 15, quad = ln >> 4;
    // phase-2 B frags straight from global (L2-resident, shared by all blocks)
    bf16x8 bo[2][4];
#pragma unroll
    for (int tt = 0; tt < 2; tt++)
#pragma unroll
        for (int s = 0; s < 4; s++)
            bo[tt][s] = *(const bf16x8*)(WTo + (tt * 16 + l15) * 128 + s * 32 + quad * 8);
    const u16* pA = sA + (w * 16 + l15) * 136 + quad * 8;
    const u16* pB = sW + l15 * 136 + quad * 8;
    f32x4 acc[8];
#pragma unroll
    for (int tt = 0; tt < 8; tt++) acc[tt] = (f32x4){0.f, 0.f, 0.f, 0.f};
#pragma unroll
    for (int s = 0; s < 4; s++) {
        bf16x8 a = *(const bf16x8*)(pA + s * 32);
#pragma unroll
        for (int tt = 0; tt < 8; tt++) {
            bf16x8 b = *(const bf16x8*)(pB + tt * 2176 + s * 32);
            acc[tt] = __builtin_amdgcn_mfma_f32_16x16x32_bf16(a, b, acc[tt], 0, 0, 0);
        }
    }
    // epilogue 1: g = lrelu(acc + agg1 + b1) -> own sA rows (bf16). No barrier needed:
    // per-wave DS ops are in-order and each wave reads/writes only rows w*16..w*16+15.
#pragma unroll
    for (int tt = 0; tt < 8; tt++) {
        int col = tt * 16 + l15;
        float bv = b1[col];
#pragma unroll
        for (int i = 0; i < 4; i++) {
            int rl = w * 16 + quad * 4 + i;
            int row = m0 + rl;
            float ag = (row < M) ? bfh(aggm[row * D_H + col]) : 0.f;
            float v = acc[tt][i] + ag + bv;
            v = v > 0.f ? v : 0.01f * v;
            sA[rl * 136 + col] = fbh(v);
        }
    }
    // phase 2: out = g @ Wout + bout
    f32x4 acc2[2];
    acc2[0] = (f32x4){0.f, 0.f, 0.f, 0.f};
    acc2[1] = (f32x4){0.f, 0.f, 0.f, 0.f};
#pragma unroll
    for (int s = 0; s < 4; s++) {
        bf16x8 g = *(const bf16x8*)(pA + s * 32);
        acc2[0] = __builtin_amdgcn_mfma_f32_16x16x32_bf16(g, bo[0][s], acc2[0], 0, 0, 0);
        acc2[1] = __builtin_amdgcn_mfma_f32_16x16x32_bf16(g, bo[1][s], acc2[1], 0, 0, 0);
    }
#pragma unroll
    for (int tt = 0; tt < 2; tt++) {
        int col = tt * 16 + l15;
        float bv = bout[col];
#pragma unroll
        for (int i = 0; i < 4; i++) {
            int row = m0 + w * 16 + quad * 4 + i;
            if (row < M) OUT[row * D_OUT + col] = acc2[tt][i] + bv;
        }
    }
}

extern "C" void kernel_launch(void* const* d_in, const int* in_sizes, int n_in,
                              void* d_out, int out_size, void* d_ws, size_t ws_size,
                              hipStream_t stream) {
    const float* x_host  = (const float*)d_in[0];
    const float* x_flow  = (const float*)d_in[1];
    const int* src_hf  = (const int*)d_in[2];
    const int* dst_hf  = (const int*)d_in[3];
    const int* src_fh  = (const int*)d_in[4];
    const int* dst_fh  = (const int*)d_in[5];
    const float* W0_hf_l = (const float*)d_in[6];
    const float* W0_hf_r = (const float*)d_in[7];
    const float* b0_hf   = (const float*)d_in[8];
    const float* W0_fh_l = (const float*)d_in[9];
    const float* W0_fh_r = (const float*)d_in[10];
    const float* b0_fh   = (const float*)d_in[11];
    const float* W1_hf_l = (const float*)d_in[12];
    const float* W1_hf_r = (const float*)d_in[13];
    const float* b1_hf   = (const float*)d_in[14];
    const float* W_out   = (const float*)d_in[18];
    const float* b_out   = (const float*)d_in[19];
    float* out = (float*)d_out;

    // workspace layout (bytes), lifetime-aliased; total ~114.2 MB, all offsets 16B-aligned
    char* ws = (char*)d_ws;
    int* off    = (int*)(ws + 0);            //   880,000
    int* csr    = (int*)(ws + 880000);       // 4,800,000
    u16* h_flow = (u16*)(ws + 5680000);      // 51,200,000 (bf16, live to end)
    u16* hT     = (u16*)(ws + 56880000);     //  5,120,000 (bf16)
    u16* agg1m  = (u16*)(ws + 62000000);     // 51,200,000 (bf16) -- region reused:
    u16* agg0f  = (u16*)(ws + 62000000);     //   25,600,000 (dead after G1)
    u16* agg0h  = (u16*)(ws + 87600000);     //    2,560,000 (dead after G2)
    u16* h_host = (u16*)(ws + 90160000);     //    5,120,000 (dead after G3)
    int* deg    = (int*)(ws + 113200000);    //   880,000
    u16* WT0_hf = (u16*)(ws + 114080000);    //    32,768
    u16* WT0_fh = (u16*)(ws + 114112768);    //    32,768
    u16* WT1_l  = (u16*)(ws + 114145536);    //    32,768
    u16* WT1_r  = (u16*)(ws + 114178304);    //    32,768
    u16* WTo    = (u16*)(ws + 114211072);    //     8,192
    int* part   = (int*)(ws + 114219264);    //       448

    hipMemsetAsync(deg, 0, NSEG * sizeof(int), stream);
    k_prep<<<34, 256, 0, stream>>>(W0_hf_l, W0_hf_r, W0_fh_l, W0_fh_r, W1_hf_l, W1_hf_r,
                                   W_out, WT0_hf, WT0_fh, WT1_l, WT1_r, WTo);
    k_count<<<(2 * NEDGE + 255) / 256, 256, 0, stream>>>(dst_hf, dst_fh, deg);
    k_scan1<<<NB, 256, 0, stream>>>(deg, part);
    k_scan2<<<1, 256, 0, stream>>>(part);
    k_scan3<<<NB, 256, 0, stream>>>(deg, part, off);
    k_fill<<<(2 * NEDGE + 255) / 256, 256, 0, stream>>>(src_hf, dst_hf, src_fh, dst_fh, off, csr);
    k_agg0<<<NSEG / 4, 256, 0, stream>>>(x_host, x_flow, off, csr, agg0f, agg0h);
    k_mfma<true, true><<<3125, 256, 0, stream>>>(agg0f, x_flow, WT0_hf, b0_hf, h_flow, N_FLOW);
    k_mfma<true, true><<<313, 256, 0, stream>>>(agg0h, x_host, WT0_fh, b0_fh, h_host, N_HOST);
    k_mfma<false, false><<<313, 256, 0, stream>>>(h_host, nullptr, WT1_l, nullptr, hT, N_HOST);
    k_agg1<<<N_FLOW / 4, 256, 0, stream>>>(hT, off, csr, agg1m);
    k_final<<<3125, 256, 0, stream>>>(h_flow, WT1_r, b1_hf, agg1m, WTo, b_out, out, N_FLOW);
}

// Round 4
// 504.730 us; speedup vs baseline: 1.5234x; 1.2201x over previous
//
#include <hip/hip_runtime.h>

// HeteroGNN on MI355X. Inputs/weights/output fp32 (per reference); intermediates bf16.
// Round 4: aggregation kernels remapped wave-per-node -> 16-threads-per-node (chunk-parallel
// gathers, 16B/lane, 64 independent load streams per wave). GEMMs unchanged (MFMA).
//   CSR build (count -> scan -> fill)
//   agg0  : seg-mean x_host->flow, x_flow->host (64d)
//   G1    : h_flow = lrelu([agg0f|x_flow] @ WT0_hf^T + b0_hf)   M=200000  (MFMA)
//   G2    : h_host = lrelu([agg0h|x_host] @ WT0_fh^T + b0_fh)   M=20000   (MFMA)
//   G3    : hT     = h_host @ W1_hf_l  (transform BEFORE mean)            (MFMA)
//   agg1  : seg-mean hT -> flow (128d)
//   G4    : out = lrelu(h_flow@W1_hf_r + agg1 + b1) @ W_out + b_out  (fused 2-phase MFMA)
// g_host dead in reference -> W1_fh_* unused.

#define N_HOST 20000
#define N_FLOW 200000
#define NEDGE  600000
#define D_IN   64
#define D_H    128
#define D_OUT  32
#define NSEG   (N_FLOW + N_HOST)
#define NB     108                 // ceil(NSEG / 2048)

typedef unsigned short u16;
typedef unsigned int   u32;
typedef short bf16x8 __attribute__((ext_vector_type(8)));
typedef float f32x4  __attribute__((ext_vector_type(4)));

__device__ __forceinline__ float bfh(u16 h) { return __uint_as_float(((u32)h) << 16); }
__device__ __forceinline__ u16 fbh(float f) {
    u32 u = __float_as_uint(f);
    return (u16)((u + 0x7fffu + ((u >> 16) & 1u)) >> 16);   // RNE
}
__device__ __forceinline__ u32 packbf(float x, float y) {
    return (u32)fbh(x) | ((u32)fbh(y) << 16);
}

// ---------------- weight pre-transpose: WT[n][k] bf16 ----------------
__global__ void k_prep(const float* __restrict__ W0_hf_l, const float* __restrict__ W0_hf_r,
                       const float* __restrict__ W0_fh_l, const float* __restrict__ W0_fh_r,
                       const float* __restrict__ W1_l, const float* __restrict__ W1_r,
                       const float* __restrict__ Wout,
                       u16* __restrict__ WT0_hf, u16* __restrict__ WT0_fh,
                       u16* __restrict__ WT1_l, u16* __restrict__ WT1_r,
                       u16* __restrict__ WTo) {
    int b = blockIdx.x, t = threadIdx.x;
    u16 tmp[8];
    if (b < 32) {
        int e = (b & 7) * 2048 + t * 8;
        int n = e >> 7, k0 = e & 127;
        if (b < 8) {
#pragma unroll
            for (int j = 0; j < 8; j++) {
                int k = k0 + j;
                tmp[j] = fbh(k < 64 ? W0_hf_l[k * D_H + n] : W0_hf_r[(k - 64) * D_H + n]);
            }
            *(uint4*)(WT0_hf + n * 128 + k0) = *(uint4*)tmp;
        } else if (b < 16) {
#pragma unroll
            for (int j = 0; j < 8; j++) {
                int k = k0 + j;
                tmp[j] = fbh(k < 64 ? W0_fh_l[k * D_H + n] : W0_fh_r[(k - 64) * D_H + n]);
            }
            *(uint4*)(WT0_fh + n * 128 + k0) = *(uint4*)tmp;
        } else if (b < 24) {
#pragma unroll
            for (int j = 0; j < 8; j++) tmp[j] = fbh(W1_l[(k0 + j) * D_H + n]);
            *(uint4*)(WT1_l + n * 128 + k0) = *(uint4*)tmp;
        } else {
#pragma unroll
            for (int j = 0; j < 8; j++) tmp[j] = fbh(W1_r[(k0 + j) * D_H + n]);
            *(uint4*)(WT1_r + n * 128 + k0) = *(uint4*)tmp;
        }
    } else {
        int e = (b - 32) * 2048 + t * 8;
        int n = e >> 7, k0 = e & 127;
#pragma unroll
        for (int j = 0; j < 8; j++) tmp[j] = fbh(Wout[(k0 + j) * D_OUT + n]);
        *(uint4*)(WTo + n * 128 + k0) = *(uint4*)tmp;
    }
}

// ---------------- CSR build ----------------
__global__ void k_count(const int* __restrict__ dst_hf, const int* __restrict__ dst_fh,
                        int* __restrict__ deg) {
    int t = blockIdx.x * 256 + threadIdx.x;
    if (t < NEDGE)               atomicAdd(&deg[dst_hf[t]], 1);
    else if (t < 2 * NEDGE)      atomicAdd(&deg[N_FLOW + dst_fh[t - NEDGE]], 1);
}

__global__ void k_scan1(const int* __restrict__ deg, int* __restrict__ part) {
    int b = blockIdx.x, t = threadIdx.x;
    int s = 0;
#pragma unroll
    for (int i = 0; i < 8; i++) {
        int idx = b * 2048 + t + i * 256;
        if (idx < NSEG) s += deg[idx];
    }
    for (int o = 32; o > 0; o >>= 1) s += __shfl_down(s, o, 64);
    __shared__ int red[4];
    int lane = t & 63, wid = t >> 6;
    if (lane == 0) red[wid] = s;
    __syncthreads();
    if (t == 0) part[b] = red[0] + red[1] + red[2] + red[3];
}

__global__ void k_scan2(int* __restrict__ part) {
    __shared__ int sp[256];
    int t = threadIdx.x;
    int v = (t < NB) ? part[t] : 0;
    sp[t] = v;
    __syncthreads();
    for (int d = 1; d < 256; d <<= 1) {
        int x = (t >= d) ? sp[t - d] : 0;
        __syncthreads();
        sp[t] += x;
        __syncthreads();
    }
    if (t < NB) part[t] = sp[t] - v;   // exclusive
}

__global__ void k_scan3(const int* __restrict__ deg, const int* __restrict__ part,
                        int* __restrict__ off) {
    __shared__ int sv[2048];
    __shared__ int ts[256];
    int b = blockIdx.x, t = threadIdx.x;
    int base = b * 2048;
#pragma unroll
    for (int i = 0; i < 8; i++) {
        int idx = base + t + i * 256;
        sv[t + i * 256] = (idx < NSEG) ? deg[idx] : 0;
    }
    __syncthreads();
    int loc[8]; int s = 0;
#pragma unroll
    for (int j = 0; j < 8; j++) { loc[j] = s; s += sv[t * 8 + j]; }
    ts[t] = s;
    __syncthreads();
    for (int d = 1; d < 256; d <<= 1) {
        int x = (t >= d) ? ts[t - d] : 0;
        __syncthreads();
        ts[t] += x;
        __syncthreads();
    }
    int b2 = part[b] + ts[t] - s;
#pragma unroll
    for (int j = 0; j < 8; j++) {
        int idx = base + t * 8 + j;
        if (idx < NSEG) off[idx] = b2 + loc[j];
    }
}

__global__ void k_fill(const int* __restrict__ src_hf, const int* __restrict__ dst_hf,
                       const int* __restrict__ src_fh, const int* __restrict__ dst_fh,
                       int* __restrict__ off, int* __restrict__ csr) {
    int t = blockIdx.x * 256 + threadIdx.x;
    if (t < NEDGE) {
        int d = dst_hf[t];
        int p = atomicAdd(&off[d], 1);
        csr[p] = src_hf[t];
    } else if (t < 2 * NEDGE) {
        int e = t - NEDGE;
        int d = dst_fh[e];
        int p = atomicAdd(&off[N_FLOW + d], 1);
        csr[p] = src_fh[e];
    }
    // post-fill: off[i] == segment END; start(i) = off[i-1] (0 for i==0)
}

// ---------------- aggregation: 16 threads per node, 16B chunk per thread ----------------
__global__ void k_agg0(const float* __restrict__ x_host, const float* __restrict__ x_flow,
                       const int* __restrict__ off, const int* __restrict__ csr,
                       u16* __restrict__ agg0f, u16* __restrict__ agg0h) {
    int t = blockIdx.x * 256 + threadIdx.x;
    int n = t >> 4;            // node
    int c = (t & 15) << 2;     // float chunk base (4 floats)
    if (n >= NSEG) return;
    int start = (n == 0) ? 0 : off[n - 1];
    int end = off[n];
    float4 acc = make_float4(0.f, 0.f, 0.f, 0.f);
    const float* xs = (n < N_FLOW) ? x_host : x_flow;
    for (int e = start; e < end; e++) {
        int s = csr[e];
        float4 v = *(const float4*)(xs + s * D_IN + c);
        acc.x += v.x; acc.y += v.y; acc.z += v.z; acc.w += v.w;
    }
    float inv = (end > start) ? 1.f / (float)(end - start) : 0.f;
    uint2 o;
    o.x = packbf(acc.x * inv, acc.y * inv);
    o.y = packbf(acc.z * inv, acc.w * inv);
    if (n < N_FLOW) *(uint2*)(agg0f + n * D_IN + c) = o;
    else            *(uint2*)(agg0h + (n - N_FLOW) * D_IN + c) = o;
}

__global__ void k_agg1(const u16* __restrict__ hT, const int* __restrict__ off,
                       const int* __restrict__ csr, u16* __restrict__ agg1m) {
    int t = blockIdx.x * 256 + threadIdx.x;
    int n = t >> 4;            // flow node
    int c = (t & 15) << 3;     // bf16 chunk base (8 elems, 16B)
    if (n >= N_FLOW) return;
    int start = (n == 0) ? 0 : off[n - 1];
    int end = off[n];
    float acc[8] = {0.f, 0.f, 0.f, 0.f, 0.f, 0.f, 0.f, 0.f};
    for (int e = start; e < end; e++) {
        int s = csr[e];
        uint4 u = *(const uint4*)(hT + s * D_H + c);
        acc[0] += __uint_as_float(u.x << 16);
        acc[1] += __uint_as_float(u.x & 0xffff0000u);
        acc[2] += __uint_as_float(u.y << 16);
        acc[3] += __uint_as_float(u.y & 0xffff0000u);
        acc[4] += __uint_as_float(u.z << 16);
        acc[5] += __uint_as_float(u.z & 0xffff0000u);
        acc[6] += __uint_as_float(u.w << 16);
        acc[7] += __uint_as_float(u.w & 0xffff0000u);
    }
    float inv = (end > start) ? 1.f / (float)(end - start) : 0.f;
    uint4 o;
    o.x = packbf(acc[0] * inv, acc[1] * inv);
    o.y = packbf(acc[2] * inv, acc[3] * inv);
    o.z = packbf(acc[4] * inv, acc[5] * inv);
    o.w = packbf(acc[6] * inv, acc[7] * inv);
    *(uint4*)(agg1m + n * D_H + c) = o;
}

// ---------------- MFMA GEMM: 64-row tile x N=128, K=128, one-shot ----------------
// A-frag: A[m=lane&15][k=quad*8+j]; B-frag: WT[n=lane&15][k=quad*8+j]; C: col=lane&15,row=quad*4+reg.
// DUAL: A = [A1 bf16 64d | A2 fp32 64d]. else A1 bf16 stride 128. OUT bf16 [M][128].
template <bool DUAL, bool RELU>
__global__ __launch_bounds__(256) void k_mfma(
    const u16* __restrict__ A1, const float* __restrict__ A2,
    const u16* __restrict__ WT, const float* __restrict__ bias,
    u16* __restrict__ OUT, int M) {
    __shared__ __align__(16) u16 sA[64 * 136];    // [r][k] pad->stride 136 (16B aligned rows)
    __shared__ __align__(16) u16 sW[128 * 136];   // [n][k]
    const int t = threadIdx.x;
    const int m0 = blockIdx.x * 64;
#pragma unroll
    for (int i = 0; i < 8; i++) {
        int q = t + i * 256;
        int row = q >> 4, seg = q & 15;
        *(uint4*)(&sW[row * 136 + seg * 8]) = *(const uint4*)(WT + row * 128 + seg * 8);
    }
#pragma unroll
    for (int i = 0; i < 4; i++) {
        int q = t + i * 256;
        int r = q >> 4, seg = q & 15;
        int row = m0 + r;
        uint4 val = make_uint4(0u, 0u, 0u, 0u);
        if (row < M) {
            if (DUAL) {
                if (seg < 8) {
                    val = *(const uint4*)(A1 + row * 64 + seg * 8);
                } else {
                    float4 f0 = *(const float4*)(A2 + row * 64 + (seg - 8) * 8);
                    float4 f1 = *(const float4*)(A2 + row * 64 + (seg - 8) * 8 + 4);
                    val.x = packbf(f0.x, f0.y); val.y = packbf(f0.z, f0.w);
                    val.z = packbf(f1.x, f1.y); val.w = packbf(f1.z, f1.w);
                }
            } else {
                val = *(const uint4*)(A1 + row * 128 + seg * 8);
            }
        }
        *(uint4*)(&sA[r * 136 + seg * 8]) = val;
    }
    __syncthreads();
    const int w = t >> 6, ln = t & 63, l15 = ln & 15, quad = ln >> 4;
    const u16* pA = sA + (w * 16 + l15) * 136 + quad * 8;
    const u16* pB = sW + l15 * 136 + quad * 8;
    f32x4 acc[8];
#pragma unroll
    for (int tt = 0; tt < 8; tt++) acc[tt] = (f32x4){0.f, 0.f, 0.f, 0.f};
#pragma unroll
    for (int s = 0; s < 4; s++) {
        bf16x8 a = *(const bf16x8*)(pA + s * 32);
#pragma unroll
        for (int tt = 0; tt < 8; tt++) {
            bf16x8 b = *(const bf16x8*)(pB + tt * 2176 + s * 32);
            acc[tt] = __builtin_amdgcn_mfma_f32_16x16x32_bf16(a, b, acc[tt], 0, 0, 0);
        }
    }
#pragma unroll
    for (int tt = 0; tt < 8; tt++) {
        int col = tt * 16 + l15;
        float bv = bias ? bias[col] : 0.f;
#pragma unroll
        for (int i = 0; i < 4; i++) {
            int row = m0 + w * 16 + quad * 4 + i;
            if (row < M) {
                float v = acc[tt][i] + bv;
                if (RELU) v = v > 0.f ? v : 0.01f * v;
                OUT[row * D_H + col] = fbh(v);
            }
        }
    }
}

// ---------------- fused final: g=lrelu(A@W1r + agg1 + b1); out=g@Wout+bout ----------------
__global__ __launch_bounds__(256) void k_final(
    const u16* __restrict__ A, const u16* __restrict__ WT1r,
    const float* __restrict__ b1, const u16* __restrict__ aggm,
    const u16* __restrict__ WTo, const float* __restrict__ bout,
    float* __restrict__ OUT, int M) {
    __shared__ __align__(16) u16 sA[64 * 136];    // phase1 A tile; phase2 g tile (wave-private rows)
    __shared__ __align__(16) u16 sW[128 * 136];
    const int t = threadIdx.x;
    const int m0 = blockIdx.x * 64;
#pragma unroll
    for (int i = 0; i < 8; i++) {
        int q = t + i * 256;
        int row = q >> 4, seg = q & 15;
        *(uint4*)(&sW[row * 136 + seg * 8]) = *(const uint4*)(WT1r + row * 128 + seg * 8);
    }
#pragma unroll
    for (int i = 0; i < 4; i++) {
        int q = t + i * 256;
        int r = q >> 4, seg = q & 15;
        int row = m0 + r;
        uint4 val = make_uint4(0u, 0u, 0u, 0u);
        if (row < M) val = *(const uint4*)(A + row * D_H + seg * 8);
        *(uint4*)(&sA[r * 136 + seg * 8]) = val;
    }
    __syncthreads();
    const int w = t >> 6, ln = t & 63, l15 = ln & 15, quad = ln >> 4;
    // phase-2 B frags straight from global (L2-resident, shared by all blocks)
    bf16x8 bo[2][4];
#pragma unroll
    for (int tt = 0; tt < 2; tt++)
#pragma unroll
        for (int s = 0; s < 4; s++)
            bo[tt][s] = *(const bf16x8*)(WTo + (tt * 16 + l15) * 128 + s * 32 + quad * 8);
    const u16* pA = sA + (w * 16 + l15) * 136 + quad * 8;
    const u16* pB = sW + l15 * 136 + quad * 8;
    f32x4 acc[8];
#pragma unroll
    for (int tt = 0; tt < 8; tt++) acc[tt] = (f32x4){0.f, 0.f, 0.f, 0.f};
#pragma unroll
    for (int s = 0; s < 4; s++) {
        bf16x8 a = *(const bf16x8*)(pA + s * 32);
#pragma unroll
        for (int tt = 0; tt < 8; tt++) {
            bf16x8 b = *(const bf16x8*)(pB + tt * 2176 + s * 32);
            acc[tt] = __builtin_amdgcn_mfma_f32_16x16x32_bf16(a, b, acc[tt], 0, 0, 0);
        }
    }
    // epilogue 1: g = lrelu(acc + agg1 + b1) -> own sA rows (bf16). No barrier needed:
    // per-wave DS ops are in-order and each wave reads/writes only rows w*16..w*16+15.
#pragma unroll
    for (int tt = 0; tt < 8; tt++) {
        int col = tt * 16 + l15;
        float bv = b1[col];
#pragma unroll
        for (int i = 0; i < 4; i++) {
            int rl = w * 16 + quad * 4 + i;
            int row = m0 + rl;
            float ag = (row < M) ? bfh(aggm[row * D_H + col]) : 0.f;
            float v = acc[tt][i] + ag + bv;
            v = v > 0.f ? v : 0.01f * v;
            sA[rl * 136 + col] = fbh(v);
        }
    }
    // phase 2: out = g @ Wout + bout
    f32x4 acc2[2];
    acc2[0] = (f32x4){0.f, 0.f, 0.f, 0.f};
    acc2[1] = (f32x4){0.f, 0.f, 0.f, 0.f};
#pragma unroll
    for (int s = 0; s < 4; s++) {
        bf16x8 g = *(const bf16x8*)(pA + s * 32);
        acc2[0] = __builtin_amdgcn_mfma_f32_16x16x32_bf16(g, bo[0][s], acc2[0], 0, 0, 0);
        acc2[1] = __builtin_amdgcn_mfma_f32_16x16x32_bf16(g, bo[1][s], acc2[1], 0, 0, 0);
    }
#pragma unroll
    for (int tt = 0; tt < 2; tt++) {
        int col = tt * 16 + l15;
        float bv = bout[col];
#pragma unroll
        for (int i = 0; i < 4; i++) {
            int row = m0 + w * 16 + quad * 4 + i;
            if (row < M) OUT[row * D_OUT + col] = acc2[tt][i] + bv;
        }
    }
}

extern "C" void kernel_launch(void* const* d_in, const int* in_sizes, int n_in,
                              void* d_out, int out_size, void* d_ws, size_t ws_size,
                              hipStream_t stream) {
    const float* x_host  = (const float*)d_in[0];
    const float* x_flow  = (const float*)d_in[1];
    const int* src_hf  = (const int*)d_in[2];
    const int* dst_hf  = (const int*)d_in[3];
    const int* src_fh  = (const int*)d_in[4];
    const int* dst_fh  = (const int*)d_in[5];
    const float* W0_hf_l = (const float*)d_in[6];
    const float* W0_hf_r = (const float*)d_in[7];
    const float* b0_hf   = (const float*)d_in[8];
    const float* W0_fh_l = (const float*)d_in[9];
    const float* W0_fh_r = (const float*)d_in[10];
    const float* b0_fh   = (const float*)d_in[11];
    const float* W1_hf_l = (const float*)d_in[12];
    const float* W1_hf_r = (const float*)d_in[13];
    const float* b1_hf   = (const float*)d_in[14];
    const float* W_out   = (const float*)d_in[18];
    const float* b_out   = (const float*)d_in[19];
    float* out = (float*)d_out;

    // workspace layout (bytes), lifetime-aliased; total ~114.2 MB, all offsets 16B-aligned
    char* ws = (char*)d_ws;
    int* off    = (int*)(ws + 0);            //   880,000
    int* csr    = (int*)(ws + 880000);       // 4,800,000
    u16* h_flow = (u16*)(ws + 5680000);      // 51,200,000 (bf16, live to end)
    u16* hT     = (u16*)(ws + 56880000);     //  5,120,000 (bf16)
    u16* agg1m  = (u16*)(ws + 62000000);     // 51,200,000 (bf16) -- region reused:
    u16* agg0f  = (u16*)(ws + 62000000);     //   25,600,000 (dead after G1)
    u16* agg0h  = (u16*)(ws + 87600000);     //    2,560,000 (dead after G2)
    u16* h_host = (u16*)(ws + 90160000);     //    5,120,000 (dead after G3)
    int* deg    = (int*)(ws + 113200000);    //   880,000
    u16* WT0_hf = (u16*)(ws + 114080000);    //    32,768
    u16* WT0_fh = (u16*)(ws + 114112768);    //    32,768
    u16* WT1_l  = (u16*)(ws + 114145536);    //    32,768
    u16* WT1_r  = (u16*)(ws + 114178304);    //    32,768
    u16* WTo    = (u16*)(ws + 114211072);    //     8,192
    int* part   = (int*)(ws + 114219264);    //       448

    hipMemsetAsync(deg, 0, NSEG * sizeof(int), stream);
    k_prep<<<34, 256, 0, stream>>>(W0_hf_l, W0_hf_r, W0_fh_l, W0_fh_r, W1_hf_l, W1_hf_r,
                                   W_out, WT0_hf, WT0_fh, WT1_l, WT1_r, WTo);
    k_count<<<(2 * NEDGE + 255) / 256, 256, 0, stream>>>(dst_hf, dst_fh, deg);
    k_scan1<<<NB, 256, 0, stream>>>(deg, part);
    k_scan2<<<1, 256, 0, stream>>>(part);
    k_scan3<<<NB, 256, 0, stream>>>(deg, part, off);
    k_fill<<<(2 * NEDGE + 255) / 256, 256, 0, stream>>>(src_hf, dst_hf, src_fh, dst_fh, off, csr);
    k_agg0<<<(NSEG * 16 + 255) / 256, 256, 0, stream>>>(x_host, x_flow, off, csr, agg0f, agg0h);
    k_mfma<true, true><<<3125, 256, 0, stream>>>(agg0f, x_flow, WT0_hf, b0_hf, h_flow, N_FLOW);
    k_mfma<true, true><<<313, 256, 0, stream>>>(agg0h, x_host, WT0_fh, b0_fh, h_host, N_HOST);
    k_mfma<false, false><<<313, 256, 0, stream>>>(h_host, nullptr, WT1_l, nullptr, hT, N_HOST);
    k_agg1<<<(N_FLOW * 16 + 255) / 256, 256, 0, stream>>>(hT, off, csr, agg1m);
    k_final<<<3125, 256, 0, stream>>>(h_flow, WT1_r, b1_hf, agg1m, WTo, b_out, out, N_FLOW);
}

// Round 5
// 415.573 us; speedup vs baseline: 1.8502x; 1.2145x over previous
//
#include <hip/hip_runtime.h>

// HeteroGNN on MI355X. Inputs/weights/output fp32 (per reference); intermediates bf16.
// Round 5: CSR build replaced by two-level binned counting sort (no global per-node atomics):
//   kb1 (bucket hist, LDS) -> scanB (275) -> kb2 (bin scatter, clustered) -> kb3 (per-bucket
//   LDS count+scan+scatter -> csr + off). Buckets monotonic in node id: flow 1024/bkt (196),
//   host 256/bkt (79) => per-bucket layout composes into exact global CSR.
//   agg0 / agg1 : seg-mean gathers, 16 threads per node (unchanged)
//   G1/G2/G3    : MFMA GEMMs (unchanged)
//   G4          : fused final MFMA (unchanged)
// g_host dead in reference -> W1_fh_* unused.

#define N_HOST 20000
#define N_FLOW 200000
#define NEDGE  600000
#define D_IN   64
#define D_H    128
#define D_OUT  32
#define NSEG   (N_FLOW + N_HOST)
#define NBKT_F 196                 // ceil(200000/1024)
#define NBKT_H 79                  // ceil(20000/256)
#define NBKT   (NBKT_F + NBKT_H)   // 275
#define NEB    586                 // ceil(1200000/2048)

typedef unsigned short u16;
typedef unsigned int   u32;
typedef short bf16x8 __attribute__((ext_vector_type(8)));
typedef float f32x4  __attribute__((ext_vector_type(4)));

__device__ __forceinline__ float bfh(u16 h) { return __uint_as_float(((u32)h) << 16); }
__device__ __forceinline__ u16 fbh(float f) {
    u32 u = __float_as_uint(f);
    return (u16)((u + 0x7fffu + ((u >> 16) & 1u)) >> 16);   // RNE
}
__device__ __forceinline__ u32 packbf(float x, float y) {
    return (u32)fbh(x) | ((u32)fbh(y) << 16);
}

// ---------------- weight pre-transpose: WT[n][k] bf16 ----------------
__global__ void k_prep(const float* __restrict__ W0_hf_l, const float* __restrict__ W0_hf_r,
                       const float* __restrict__ W0_fh_l, const float* __restrict__ W0_fh_r,
                       const float* __restrict__ W1_l, const float* __restrict__ W1_r,
                       const float* __restrict__ Wout,
                       u16* __restrict__ WT0_hf, u16* __restrict__ WT0_fh,
                       u16* __restrict__ WT1_l, u16* __restrict__ WT1_r,
                       u16* __restrict__ WTo) {
    int b = blockIdx.x, t = threadIdx.x;
    u16 tmp[8];
    if (b < 32) {
        int e = (b & 7) * 2048 + t * 8;
        int n = e >> 7, k0 = e & 127;
        if (b < 8) {
#pragma unroll
            for (int j = 0; j < 8; j++) {
                int k = k0 + j;
                tmp[j] = fbh(k < 64 ? W0_hf_l[k * D_H + n] : W0_hf_r[(k - 64) * D_H + n]);
            }
            *(uint4*)(WT0_hf + n * 128 + k0) = *(uint4*)tmp;
        } else if (b < 16) {
#pragma unroll
            for (int j = 0; j < 8; j++) {
                int k = k0 + j;
                tmp[j] = fbh(k < 64 ? W0_fh_l[k * D_H + n] : W0_fh_r[(k - 64) * D_H + n]);
            }
            *(uint4*)(WT0_fh + n * 128 + k0) = *(uint4*)tmp;
        } else if (b < 24) {
#pragma unroll
            for (int j = 0; j < 8; j++) tmp[j] = fbh(W1_l[(k0 + j) * D_H + n]);
            *(uint4*)(WT1_l + n * 128 + k0) = *(uint4*)tmp;
        } else {
#pragma unroll
            for (int j = 0; j < 8; j++) tmp[j] = fbh(W1_r[(k0 + j) * D_H + n]);
            *(uint4*)(WT1_r + n * 128 + k0) = *(uint4*)tmp;
        }
    } else {
        int e = (b - 32) * 2048 + t * 8;
        int n = e >> 7, k0 = e & 127;
#pragma unroll
        for (int j = 0; j < 8; j++) tmp[j] = fbh(Wout[(k0 + j) * D_OUT + n]);
        *(uint4*)(WTo + n * 128 + k0) = *(uint4*)tmp;
    }
}

// ---------------- binned CSR build ----------------
__device__ __forceinline__ int bucket_of(int combined_node) {
    return (combined_node < N_FLOW) ? (combined_node >> 10)
                                    : (NBKT_F + ((combined_node - N_FLOW) >> 8));
}

__global__ void kb1(const int* __restrict__ dst_hf, const int* __restrict__ dst_fh,
                    int* __restrict__ bcnt) {
    __shared__ int h[NBKT];
    int t = threadIdx.x;
    for (int j = t; j < NBKT; j += 256) h[j] = 0;
    __syncthreads();
    int base = blockIdx.x * 2048;
#pragma unroll
    for (int i = 0; i < 8; i++) {
        int e = base + t + i * 256;
        if (e < 2 * NEDGE) {
            int bkt = (e < NEDGE) ? (dst_hf[e] >> 10)
                                  : (NBKT_F + (dst_fh[e - NEDGE] >> 8));
            atomicAdd(&h[bkt], 1);
        }
    }
    __syncthreads();
    for (int j = t; j < NBKT; j += 256)
        if (h[j]) atomicAdd(&bcnt[j], h[j]);
}

__global__ void scanB(const int* __restrict__ bcnt, int* __restrict__ ebase) {
    __shared__ int sp[512];
    int t = threadIdx.x;
    int v = (t < NBKT) ? bcnt[t] : 0;
    sp[t] = v;
    __syncthreads();
    for (int d = 1; d < 512; d <<= 1) {
        int x = (t >= d) ? sp[t - d] : 0;
        __syncthreads();
        sp[t] += x;
        __syncthreads();
    }
    if (t < NBKT) ebase[t] = sp[t] - v;   // exclusive
    if (t == NBKT - 1) ebase[NBKT] = sp[t];
}

__global__ void kb2(const int* __restrict__ src_hf, const int* __restrict__ dst_hf,
                    const int* __restrict__ src_fh, const int* __restrict__ dst_fh,
                    const int* __restrict__ ebase, int* __restrict__ bcur,
                    int2* __restrict__ binE) {
    __shared__ int lh[NBKT];   // per-block per-bucket count
    __shared__ int lb[NBKT];   // per-block per-bucket global base (relative)
    int t = threadIdx.x;
    for (int j = t; j < NBKT; j += 256) lh[j] = 0;
    __syncthreads();
    int base = blockIdx.x * 2048;
    int mybkt[8], myrank[8], mysrc[8], mydst[8];
#pragma unroll
    for (int i = 0; i < 8; i++) {
        int e = base + t + i * 256;
        mybkt[i] = -1;
        if (e < 2 * NEDGE) {
            int s, d;
            if (e < NEDGE) { s = src_hf[e]; d = dst_hf[e]; }
            else           { s = src_fh[e - NEDGE]; d = dst_fh[e - NEDGE] + N_FLOW; }
            int bkt = bucket_of(d);
            mybkt[i] = bkt; mysrc[i] = s; mydst[i] = d;
            myrank[i] = atomicAdd(&lh[bkt], 1);
        }
    }
    __syncthreads();
    for (int j = t; j < NBKT; j += 256)
        lb[j] = lh[j] ? atomicAdd(&bcur[j], lh[j]) : 0;
    __syncthreads();
#pragma unroll
    for (int i = 0; i < 8; i++) {
        if (mybkt[i] >= 0) {
            int pos = ebase[mybkt[i]] + lb[mybkt[i]] + myrank[i];
            binE[pos] = make_int2(mysrc[i], mydst[i]);
        }
    }
}

// one block per bucket: LDS degree count -> scan -> scatter csr + write off (segment ENDs)
__global__ __launch_bounds__(256) void kb3(const int2* __restrict__ binE,
                                           const int* __restrict__ ebase,
                                           int* __restrict__ off, int* __restrict__ csr) {
    __shared__ int deg[1024];
    __shared__ int ts[256];
    int b = blockIdx.x, t = threadIdx.x;
    int nbase, ncnt;
    if (b < NBKT_F) { nbase = b << 10; ncnt = min(1024, N_FLOW - nbase); }
    else { nbase = N_FLOW + ((b - NBKT_F) << 8); ncnt = min(256, NSEG - nbase); }
    int e0 = ebase[b], e1 = ebase[b + 1];
    for (int i = t; i < 1024; i += 256) deg[i] = 0;
    __syncthreads();
    for (int e = e0 + t; e < e1; e += 256) {
        int2 p = binE[e];
        atomicAdd(&deg[p.y - nbase], 1);
    }
    __syncthreads();
    int loc[4]; int s = 0;
#pragma unroll
    for (int j = 0; j < 4; j++) { loc[j] = s; s += deg[t * 4 + j]; }
    ts[t] = s;
    __syncthreads();
    for (int d = 1; d < 256; d <<= 1) {
        int x = (t >= d) ? ts[t - d] : 0;
        __syncthreads();
        ts[t] += x;
        __syncthreads();
    }
    int base2 = e0 + ts[t] - s;
    int dsave[4];
#pragma unroll
    for (int j = 0; j < 4; j++) dsave[j] = deg[t * 4 + j];
    __syncthreads();
#pragma unroll
    for (int j = 0; j < 4; j++) {
        int idx = t * 4 + j;
        int st = base2 + loc[j];
        deg[idx] = st;                              // repurpose as cursor (absolute csr pos)
        if (idx < ncnt) off[nbase + idx] = st + dsave[j];   // segment END
    }
    __syncthreads();
    for (int e = e0 + t; e < e1; e += 256) {
        int2 p = binE[e];
        int r = atomicAdd(&deg[p.y - nbase], 1);
        csr[r] = p.x;
    }
}

// ---------------- aggregation: 16 threads per node, 16B chunk per thread ----------------
__global__ void k_agg0(const float* __restrict__ x_host, const float* __restrict__ x_flow,
                       const int* __restrict__ off, const int* __restrict__ csr,
                       u16* __restrict__ agg0f, u16* __restrict__ agg0h) {
    int t = blockIdx.x * 256 + threadIdx.x;
    int n = t >> 4;            // node
    int c = (t & 15) << 2;     // float chunk base (4 floats)
    if (n >= NSEG) return;
    int start = (n == 0) ? 0 : off[n - 1];
    int end = off[n];
    float4 acc = make_float4(0.f, 0.f, 0.f, 0.f);
    const float* xs = (n < N_FLOW) ? x_host : x_flow;
    for (int e = start; e < end; e++) {
        int s = csr[e];
        float4 v = *(const float4*)(xs + s * D_IN + c);
        acc.x += v.x; acc.y += v.y; acc.z += v.z; acc.w += v.w;
    }
    float inv = (end > start) ? 1.f / (float)(end - start) : 0.f;
    uint2 o;
    o.x = packbf(acc.x * inv, acc.y * inv);
    o.y = packbf(acc.z * inv, acc.w * inv);
    if (n < N_FLOW) *(uint2*)(agg0f + n * D_IN + c) = o;
    else            *(uint2*)(agg0h + (n - N_FLOW) * D_IN + c) = o;
}

__global__ void k_agg1(const u16* __restrict__ hT, const int* __restrict__ off,
                       const int* __restrict__ csr, u16* __restrict__ agg1m) {
    int t = blockIdx.x * 256 + threadIdx.x;
    int n = t >> 4;            // flow node
    int c = (t & 15) << 3;     // bf16 chunk base (8 elems, 16B)
    if (n >= N_FLOW) return;
    int start = (n == 0) ? 0 : off[n - 1];
    int end = off[n];
    float acc[8] = {0.f, 0.f, 0.f, 0.f, 0.f, 0.f, 0.f, 0.f};
    for (int e = start; e < end; e++) {
        int s = csr[e];
        uint4 u = *(const uint4*)(hT + s * D_H + c);
        acc[0] += __uint_as_float(u.x << 16);
        acc[1] += __uint_as_float(u.x & 0xffff0000u);
        acc[2] += __uint_as_float(u.y << 16);
        acc[3] += __uint_as_float(u.y & 0xffff0000u);
        acc[4] += __uint_as_float(u.z << 16);
        acc[5] += __uint_as_float(u.z & 0xffff0000u);
        acc[6] += __uint_as_float(u.w << 16);
        acc[7] += __uint_as_float(u.w & 0xffff0000u);
    }
    float inv = (end > start) ? 1.f / (float)(end - start) : 0.f;
    uint4 o;
    o.x = packbf(acc[0] * inv, acc[1] * inv);
    o.y = packbf(acc[2] * inv, acc[3] * inv);
    o.z = packbf(acc[4] * inv, acc[5] * inv);
    o.w = packbf(acc[6] * inv, acc[7] * inv);
    *(uint4*)(agg1m + n * D_H + c) = o;
}

// ---------------- MFMA GEMM: 64-row tile x N=128, K=128, one-shot ----------------
// A-frag: A[m=lane&15][k=quad*8+j]; B-frag: WT[n=lane&15][k=quad*8+j]; C: col=lane&15,row=quad*4+reg.
// DUAL: A = [A1 bf16 64d | A2 fp32 64d]. else A1 bf16 stride 128. OUT bf16 [M][128].
template <bool DUAL, bool RELU>
__global__ __launch_bounds__(256) void k_mfma(
    const u16* __restrict__ A1, const float* __restrict__ A2,
    const u16* __restrict__ WT, const float* __restrict__ bias,
    u16* __restrict__ OUT, int M) {
    __shared__ __align__(16) u16 sA[64 * 136];    // [r][k] pad->stride 136 (16B aligned rows)
    __shared__ __align__(16) u16 sW[128 * 136];   // [n][k]
    const int t = threadIdx.x;
    const int m0 = blockIdx.x * 64;
#pragma unroll
    for (int i = 0; i < 8; i++) {
        int q = t + i * 256;
        int row = q >> 4, seg = q & 15;
        *(uint4*)(&sW[row * 136 + seg * 8]) = *(const uint4*)(WT + row * 128 + seg * 8);
    }
#pragma unroll
    for (int i = 0; i < 4; i++) {
        int q = t + i * 256;
        int r = q >> 4, seg = q & 15;
        int row = m0 + r;
        uint4 val = make_uint4(0u, 0u, 0u, 0u);
        if (row < M) {
            if (DUAL) {
                if (seg < 8) {
                    val = *(const uint4*)(A1 + row * 64 + seg * 8);
                } else {
                    float4 f0 = *(const float4*)(A2 + row * 64 + (seg - 8) * 8);
                    float4 f1 = *(const float4*)(A2 + row * 64 + (seg - 8) * 8 + 4);
                    val.x = packbf(f0.x, f0.y); val.y = packbf(f0.z, f0.w);
                    val.z = packbf(f1.x, f1.y); val.w = packbf(f1.z, f1.w);
                }
            } else {
                val = *(const uint4*)(A1 + row * 128 + seg * 8);
            }
        }
        *(uint4*)(&sA[r * 136 + seg * 8]) = val;
    }
    __syncthreads();
    const int w = t >> 6, ln = t & 63, l15 = ln & 15, quad = ln >> 4;
    const u16* pA = sA + (w * 16 + l15) * 136 + quad * 8;
    const u16* pB = sW + l15 * 136 + quad * 8;
    f32x4 acc[8];
#pragma unroll
    for (int tt = 0; tt < 8; tt++) acc[tt] = (f32x4){0.f, 0.f, 0.f, 0.f};
#pragma unroll
    for (int s = 0; s < 4; s++) {
        bf16x8 a = *(const bf16x8*)(pA + s * 32);
#pragma unroll
        for (int tt = 0; tt < 8; tt++) {
            bf16x8 b = *(const bf16x8*)(pB + tt * 2176 + s * 32);
            acc[tt] = __builtin_amdgcn_mfma_f32_16x16x32_bf16(a, b, acc[tt], 0, 0, 0);
        }
    }
#pragma unroll
    for (int tt = 0; tt < 8; tt++) {
        int col = tt * 16 + l15;
        float bv = bias ? bias[col] : 0.f;
#pragma unroll
        for (int i = 0; i < 4; i++) {
            int row = m0 + w * 16 + quad * 4 + i;
            if (row < M) {
                float v = acc[tt][i] + bv;
                if (RELU) v = v > 0.f ? v : 0.01f * v;
                OUT[row * D_H + col] = fbh(v);
            }
        }
    }
}

// ---------------- fused final: g=lrelu(A@W1r + agg1 + b1); out=g@Wout+bout ----------------
__global__ __launch_bounds__(256) void k_final(
    const u16* __restrict__ A, const u16* __restrict__ WT1r,
    const float* __restrict__ b1, const u16* __restrict__ aggm,
    const u16* __restrict__ WTo, const float* __restrict__ bout,
    float* __restrict__ OUT, int M) {
    __shared__ __align__(16) u16 sA[64 * 136];    // phase1 A tile; phase2 g tile (wave-private rows)
    __shared__ __align__(16) u16 sW[128 * 136];
    const int t = threadIdx.x;
    const int m0 = blockIdx.x * 64;
#pragma unroll
    for (int i = 0; i < 8; i++) {
        int q = t + i * 256;
        int row = q >> 4, seg = q & 15;
        *(uint4*)(&sW[row * 136 + seg * 8]) = *(const uint4*)(WT1r + row * 128 + seg * 8);
    }
#pragma unroll
    for (int i = 0; i < 4; i++) {
        int q = t + i * 256;
        int r = q >> 4, seg = q & 15;
        int row = m0 + r;
        uint4 val = make_uint4(0u, 0u, 0u, 0u);
        if (row < M) val = *(const uint4*)(A + row * D_H + seg * 8);
        *(uint4*)(&sA[r * 136 + seg * 8]) = val;
    }
    __syncthreads();
    const int w = t >> 6, ln = t & 63, l15 = ln & 15, quad = ln >> 4;
    // phase-2 B frags straight from global (L2-resident, shared by all blocks)
    bf16x8 bo[2][4];
#pragma unroll
    for (int tt = 0; tt < 2; tt++)
#pragma unroll
        for (int s = 0; s < 4; s++)
            bo[tt][s] = *(const bf16x8*)(WTo + (tt * 16 + l15) * 128 + s * 32 + quad * 8);
    const u16* pA = sA + (w * 16 + l15) * 136 + quad * 8;
    const u16* pB = sW + l15 * 136 + quad * 8;
    f32x4 acc[8];
#pragma unroll
    for (int tt = 0; tt < 8; tt++) acc[tt] = (f32x4){0.f, 0.f, 0.f, 0.f};
#pragma unroll
    for (int s = 0; s < 4; s++) {
        bf16x8 a = *(const bf16x8*)(pA + s * 32);
#pragma unroll
        for (int tt = 0; tt < 8; tt++) {
            bf16x8 b = *(const bf16x8*)(pB + tt * 2176 + s * 32);
            acc[tt] = __builtin_amdgcn_mfma_f32_16x16x32_bf16(a, b, acc[tt], 0, 0, 0);
        }
    }
    // epilogue 1: g = lrelu(acc + agg1 + b1) -> own sA rows (bf16). No barrier needed:
    // per-wave DS ops are in-order and each wave reads/writes only rows w*16..w*16+15.
#pragma unroll
    for (int tt = 0; tt < 8; tt++) {
        int col = tt * 16 + l15;
        float bv = b1[col];
#pragma unroll
        for (int i = 0; i < 4; i++) {
            int rl = w * 16 + quad * 4 + i;
            int row = m0 + rl;
            float ag = (row < M) ? bfh(aggm[row * D_H + col]) : 0.f;
            float v = acc[tt][i] + ag + bv;
            v = v > 0.f ? v : 0.01f * v;
            sA[rl * 136 + col] = fbh(v);
        }
    }
    // phase 2: out = g @ Wout + bout
    f32x4 acc2[2];
    acc2[0] = (f32x4){0.f, 0.f, 0.f, 0.f};
    acc2[1] = (f32x4){0.f, 0.f, 0.f, 0.f};
#pragma unroll
    for (int s = 0; s < 4; s++) {
        bf16x8 g = *(const bf16x8*)(pA + s * 32);
        acc2[0] = __builtin_amdgcn_mfma_f32_16x16x32_bf16(g, bo[0][s], acc2[0], 0, 0, 0);
        acc2[1] = __builtin_amdgcn_mfma_f32_16x16x32_bf16(g, bo[1][s], acc2[1], 0, 0, 0);
    }
#pragma unroll
    for (int tt = 0; tt < 2; tt++) {
        int col = tt * 16 + l15;
        float bv = bout[col];
#pragma unroll
        for (int i = 0; i < 4; i++) {
            int row = m0 + w * 16 + quad * 4 + i;
            if (row < M) OUT[row * D_OUT + col] = acc2[tt][i] + bv;
        }
    }
}

extern "C" void kernel_launch(void* const* d_in, const int* in_sizes, int n_in,
                              void* d_out, int out_size, void* d_ws, size_t ws_size,
                              hipStream_t stream) {
    const float* x_host  = (const float*)d_in[0];
    const float* x_flow  = (const float*)d_in[1];
    const int* src_hf  = (const int*)d_in[2];
    const int* dst_hf  = (const int*)d_in[3];
    const int* src_fh  = (const int*)d_in[4];
    const int* dst_fh  = (const int*)d_in[5];
    const float* W0_hf_l = (const float*)d_in[6];
    const float* W0_hf_r = (const float*)d_in[7];
    const float* b0_hf   = (const float*)d_in[8];
    const float* W0_fh_l = (const float*)d_in[9];
    const float* W0_fh_r = (const float*)d_in[10];
    const float* b0_fh   = (const float*)d_in[11];
    const float* W1_hf_l = (const float*)d_in[12];
    const float* W1_hf_r = (const float*)d_in[13];
    const float* b1_hf   = (const float*)d_in[14];
    const float* W_out   = (const float*)d_in[18];
    const float* b_out   = (const float*)d_in[19];
    float* out = (float*)d_out;

    // workspace layout (bytes), lifetime-aliased; total ~114.2 MB, all offsets 16B-aligned
    char* ws = (char*)d_ws;
    int* off    = (int*)(ws + 0);            //   880,000
    int* csr    = (int*)(ws + 880000);       // 4,800,000
    u16* h_flow = (u16*)(ws + 5680000);      // 51,200,000 (bf16, live to end)
    u16* hT     = (u16*)(ws + 56880000);     //  5,120,000 (bf16)
    u16* agg1m  = (u16*)(ws + 62000000);     // 51,200,000 (bf16) -- region reused:
    int2* binE  = (int2*)(ws + 62000000);    //    9,600,000 (dead before agg0f written)
    u16* agg0f  = (u16*)(ws + 62000000);     //   25,600,000 (dead after G1)
    u16* agg0h  = (u16*)(ws + 87600000);     //    2,560,000 (dead after G2)
    u16* h_host = (u16*)(ws + 90160000);     //    5,120,000 (dead after G3)
    int* bcnt   = (int*)(ws + 113200000);    //     1,104 (+pad)
    int* bcur   = (int*)(ws + 113201280);    //     1,104
    int* ebase  = (int*)(ws + 113202560);    //     1,108
    u16* WT0_hf = (u16*)(ws + 114080000);    //    32,768
    u16* WT0_fh = (u16*)(ws + 114112768);    //    32,768
    u16* WT1_l  = (u16*)(ws + 114145536);    //    32,768
    u16* WT1_r  = (u16*)(ws + 114178304);    //    32,768
    u16* WTo    = (u16*)(ws + 114211072);    //     8,192

    hipMemsetAsync(bcnt, 0, 2560, stream);   // bcnt + bcur
    k_prep<<<34, 256, 0, stream>>>(W0_hf_l, W0_hf_r, W0_fh_l, W0_fh_r, W1_hf_l, W1_hf_r,
                                   W_out, WT0_hf, WT0_fh, WT1_l, WT1_r, WTo);
    kb1<<<NEB, 256, 0, stream>>>(dst_hf, dst_fh, bcnt);
    scanB<<<1, 512, 0, stream>>>(bcnt, ebase);
    kb2<<<NEB, 256, 0, stream>>>(src_hf, dst_hf, src_fh, dst_fh, ebase, bcur, binE);
    kb3<<<NBKT, 256, 0, stream>>>(binE, ebase, off, csr);
    k_agg0<<<(NSEG * 16 + 255) / 256, 256, 0, stream>>>(x_host, x_flow, off, csr, agg0f, agg0h);
    k_mfma<true, true><<<3125, 256, 0, stream>>>(agg0f, x_flow, WT0_hf, b0_hf, h_flow, N_FLOW);
    k_mfma<true, true><<<313, 256, 0, stream>>>(agg0h, x_host, WT0_fh, b0_fh, h_host, N_HOST);
    k_mfma<false, false><<<313, 256, 0, stream>>>(h_host, nullptr, WT1_l, nullptr, hT, N_HOST);
    k_agg1<<<(N_FLOW * 16 + 255) / 256, 256, 0, stream>>>(hT, off, csr, agg1m);
    k_final<<<3125, 256, 0, stream>>>(h_flow, WT1_r, b1_hf, agg1m, WTo, b_out, out, N_FLOW);
}